// Round 1
// baseline (1405.724 us; speedup 1.0000x reference)
//
#include <hip/hip_runtime.h>

// BandSplit: per-band gather -> linear(din->128) -> linear(128->din) -> masked
// scatter-add -> divide by OLA window.
// Round 1: correct fp32 baseline, register-blocked (8m x 4o per thread).
// K=64 bands, COUT=128, CIN=2, B=4, T=1024, F=1025. W (~106) read from in_sizes.

#define K_BANDS 64
#define COUT_D  128
#define CIN_C   2
#define T_DIM   1024
#define B_DIM   4
#define F_DIM   1025
#define M_TILE  64
#define MAXW    160
#define MAXDIN  (MAXW * CIN_C)

__global__ __launch_bounds__(256) void bs_main(
    const float* __restrict__ x,       // (B, C, T, F)
    const float* __restrict__ pre_w,   // (K, din, COUT)
    const float* __restrict__ pre_b,   // (K, COUT)
    const float* __restrict__ post_w,  // (K, COUT, din)
    const float* __restrict__ post_b,  // (K, din)
    const int*   __restrict__ idx,     // (K, W)
    const float* __restrict__ melw,    // (K, W)
    const float* __restrict__ mask,    // (K, W)
    float* __restrict__ out,           // (B, C, T, F), pre-zeroed
    int W, int din)
{
    __shared__ int   s_idx[MAXW];
    __shared__ float s_wts[MAXW];
    __shared__ float s_g[M_TILE][MAXDIN];   // gathered inputs, g[m][i]
    __shared__ float s_z[M_TILE][COUT_D];   // latent, z[m][o]

    const int k      = blockIdx.x;
    const int m_base = blockIdx.y * M_TILE;
    const int tid    = threadIdx.x;

    // ---- stage band index/weights ----
    for (int j = tid; j < W; j += 256) {
        s_idx[j] = idx[k * W + j];
        s_wts[j] = melw[k * W + j] * mask[k * W + j];
    }
    __syncthreads();

    // ---- stage gathered G tile: g[m][i] = x[b][c][t][idx[k][i/2]] * wts ----
    for (int m = 0; m < M_TILE; ++m) {
        const int mr = m_base + m;
        const int b  = mr >> 10;       // T = 1024
        const int t  = mr & 1023;
        const float* xb = x + ((size_t)(b * CIN_C) * T_DIM + t) * F_DIM;
        for (int i = tid; i < din; i += 256) {
            const int wi = i >> 1;
            const int c  = i & 1;
            s_g[m][i] = xb[(size_t)c * T_DIM * F_DIM + s_idx[wi]] * s_wts[wi];
        }
    }
    __syncthreads();

    // ---- Z phase: z[m][o] = sum_i g[m][i] * pre_w[k][i][o] + pre_b[k][o] ----
    {
        const int og = tid & 31;       // 32 o-groups of 4
        const int mg = tid >> 5;       // 8 m-groups of 8
        const int o0 = og * 4;
        const int m0 = mg * 8;
        const float* pw = pre_w + (size_t)k * din * COUT_D;  // [i][o]

        float acc[8][4];
#pragma unroll
        for (int mm = 0; mm < 8; ++mm)
#pragma unroll
            for (int oo = 0; oo < 4; ++oo)
                acc[mm][oo] = pre_b[k * COUT_D + o0 + oo];

        float4 wbuf[4];
#pragma unroll
        for (int c = 0; c < 4; ++c)
            wbuf[c] = (c < din) ? *(const float4*)(pw + (size_t)c * COUT_D + o0)
                                : make_float4(0.f, 0.f, 0.f, 0.f);

        for (int i0 = 0; i0 < din; i0 += 4) {
            float4 cur[4];
#pragma unroll
            for (int c = 0; c < 4; ++c) cur[c] = wbuf[c];
            // prefetch next 4 rows
#pragma unroll
            for (int c = 0; c < 4; ++c) {
                const int ip = i0 + 4 + c;
                if (ip < din) wbuf[c] = *(const float4*)(pw + (size_t)ip * COUT_D + o0);
            }
#pragma unroll
            for (int c = 0; c < 4; ++c) {
                const int i = i0 + c;
                if (i < din) {
                    float g[8];
#pragma unroll
                    for (int mm = 0; mm < 8; ++mm) g[mm] = s_g[m0 + mm][i];
#pragma unroll
                    for (int mm = 0; mm < 8; ++mm) {
                        acc[mm][0] += g[mm] * cur[c].x;
                        acc[mm][1] += g[mm] * cur[c].y;
                        acc[mm][2] += g[mm] * cur[c].z;
                        acc[mm][3] += g[mm] * cur[c].w;
                    }
                }
            }
        }
#pragma unroll
        for (int mm = 0; mm < 8; ++mm)
            *(float4*)&s_z[m0 + mm][o0] =
                make_float4(acc[mm][0], acc[mm][1], acc[mm][2], acc[mm][3]);
    }
    __syncthreads();

    // ---- Y phase + scatter: y[m][i] = (sum_d z[m][d]*post_w[k][d][i] + post_b)*mask ----
    {
        const int ig_count = (din + 3) >> 2;
        const int items    = ig_count * 8;
        const float* pw = post_w + (size_t)k * COUT_D * din;  // [d][i]

        for (int p = tid; p < items; p += 256) {
            const int mg = p & 7;
            const int m0 = mg * 8;
            const int ig = p >> 3;
            const int i0 = ig * 4;

            float acc[8][4];
#pragma unroll
            for (int mm = 0; mm < 8; ++mm)
#pragma unroll
                for (int c = 0; c < 4; ++c) acc[mm][c] = 0.f;

            float wb[4][4];
#pragma unroll
            for (int dd = 0; dd < 4; ++dd)
#pragma unroll
                for (int c = 0; c < 4; ++c)
                    wb[dd][c] = (i0 + c < din) ? pw[(size_t)dd * din + i0 + c] : 0.f;

            for (int d0 = 0; d0 < COUT_D; d0 += 4) {
                float cw[4][4];
#pragma unroll
                for (int dd = 0; dd < 4; ++dd)
#pragma unroll
                    for (int c = 0; c < 4; ++c) cw[dd][c] = wb[dd][c];
                const int dn = d0 + 4;
                if (dn < COUT_D) {
#pragma unroll
                    for (int dd = 0; dd < 4; ++dd)
#pragma unroll
                        for (int c = 0; c < 4; ++c)
                            wb[dd][c] = (i0 + c < din)
                                          ? pw[(size_t)(dn + dd) * din + i0 + c] : 0.f;
                }
#pragma unroll
                for (int dd = 0; dd < 4; ++dd) {
                    const int d = d0 + dd;
                    float z[8];
#pragma unroll
                    for (int mm = 0; mm < 8; ++mm) z[mm] = s_z[m0 + mm][d];
#pragma unroll
                    for (int mm = 0; mm < 8; ++mm) {
                        acc[mm][0] += z[mm] * cw[dd][0];
                        acc[mm][1] += z[mm] * cw[dd][1];
                        acc[mm][2] += z[mm] * cw[dd][2];
                        acc[mm][3] += z[mm] * cw[dd][3];
                    }
                }
            }

            // scatter (skip masked/pad entries)
#pragma unroll
            for (int c = 0; c < 4; ++c) {
                const int i = i0 + c;
                if (i >= din) continue;
                const int   wi = i >> 1;
                const float wt = s_wts[wi];
                if (wt == 0.f) continue;
                const int ch = i & 1;
                const int f  = s_idx[wi];
                const float pb = post_b[k * din + i];
#pragma unroll
                for (int mm = 0; mm < 8; ++mm) {
                    const int mr = m_base + m0 + mm;
                    const int b  = mr >> 10;
                    const int t  = mr & 1023;
                    atomicAdd(out + ((size_t)(b * CIN_C + ch) * T_DIM + t) * F_DIM + f,
                              acc[mm][c] + pb);
                }
            }
        }
    }
}

__global__ __launch_bounds__(256) void bs_scale(float* __restrict__ out,
                                                const float* __restrict__ ola,
                                                int total)
{
    const int n = blockIdx.x * 256 + threadIdx.x;
    if (n < total) {
        out[n] = out[n] / ola[n % F_DIM];
    }
}

extern "C" void kernel_launch(void* const* d_in, const int* in_sizes, int n_in,
                              void* d_out, int out_size, void* d_ws, size_t ws_size,
                              hipStream_t stream) {
    const float* x      = (const float*)d_in[0];
    const float* pre_w  = (const float*)d_in[1];
    const float* pre_b  = (const float*)d_in[2];
    const float* post_w = (const float*)d_in[3];
    const float* post_b = (const float*)d_in[4];
    const int*   idx    = (const int*)d_in[5];
    const float* melw   = (const float*)d_in[6];
    const float* mask   = (const float*)d_in[7];
    const float* ola    = (const float*)d_in[8];
    float* out = (float*)d_out;

    const int W   = in_sizes[5] / K_BANDS;   // max band width (~106)
    const int din = W * CIN_C;

    // zero the output accumulator every call (harness doesn't re-poison)
    hipMemsetAsync(d_out, 0, (size_t)out_size * sizeof(float), stream);

    dim3 grid(K_BANDS, (B_DIM * T_DIM) / M_TILE);
    bs_main<<<grid, 256, 0, stream>>>(x, pre_w, pre_b, post_w, post_b,
                                      idx, melw, mask, out, W, din);

    bs_scale<<<(out_size + 255) / 256, 256, 0, stream>>>(out, ola, out_size);
}

// Round 2
// 226.862 us; speedup vs baseline: 6.1964x; 6.1964x over previous
//
#include <hip/hip_runtime.h>

// BandSplit via bf16 MFMA (16x16x32), fragment-packed weights in d_ws.
// grid = (64 bands, 64 m-tiles of 64 rows). Per block: gather (contiguous
// band bins, coalesced) -> LDS bf16 -> GEMM1 (din->128) -> z in LDS bf16 ->
// GEMM2 (128->din) -> scatter atomicAdd with mask & 1/ola folded in.

#define K_BANDS 64
#define COUT_D  128
#define T_DIM   1024
#define B_DIM   4
#define F_DIM   1025
#define M_TILE  64
#define WPAD    112      // padded max band width (actual W ~106)
#define DINP    (2*WPAD) // 224, padded din (7 k-steps of 32)
#define SG_LD   232      // s_g row stride in bf16 (116 dwords, %32=20 -> spread)
#define SZ_LD   136      // s_z row stride in bf16 (68 dwords,  %32=4  -> spread)
#define NKT1    7        // DINP/32
#define NKT2    4        // 128/32
#define NCT1    8        // 128/16
#define NCT2    14       // DINP/16

typedef __attribute__((ext_vector_type(8))) short bf16x8;
typedef __attribute__((ext_vector_type(4))) float f32x4;

__device__ __forceinline__ unsigned short f2bf(float f) {
    unsigned u = __builtin_bit_cast(unsigned, f);
    u += 0x7FFFu + ((u >> 16) & 1u);          // round-to-nearest-even
    return (unsigned short)(u >> 16);
}

// ---- pack pre_w (K, din, 128) f32 -> fragment order (k, kt, ct, lane, 8) bf16
__global__ __launch_bounds__(256) void bs_pack_pre(
    const float* __restrict__ pre_w, unsigned short* __restrict__ dst, int din)
{
    const int k = blockIdx.x, kt = blockIdx.y;
    for (int q = threadIdx.x; q < NCT1 * 64; q += 256) {
        const int ct = q >> 6, lane = q & 63;
        const int col = lane & 15, kg = lane >> 4;
        unsigned short v[8];
#pragma unroll
        for (int j = 0; j < 8; ++j) {
            const int i = kt * 32 + kg * 8 + j;
            const float f = (i < din)
                ? pre_w[((size_t)k * din + i) * COUT_D + ct * 16 + col] : 0.f;
            v[j] = f2bf(f);
        }
        unsigned short* o = dst + ((((size_t)k * NKT1 + kt) * NCT1 + ct) * 64 + lane) * 8;
        *(ushort4*)(o)     = make_ushort4(v[0], v[1], v[2], v[3]);
        *(ushort4*)(o + 4) = make_ushort4(v[4], v[5], v[6], v[7]);
    }
}

// ---- pack post_w (K, 128, din) f32 -> fragment order (k, kt, ct, lane, 8) bf16
__global__ __launch_bounds__(256) void bs_pack_post(
    const float* __restrict__ post_w, unsigned short* __restrict__ dst, int din)
{
    const int k = blockIdx.x, kt = blockIdx.y;   // kt in [0,4)
    for (int q = threadIdx.x; q < NCT2 * 64; q += 256) {
        const int ct = q >> 6, lane = q & 63;
        const int col = lane & 15, kg = lane >> 4;
        unsigned short v[8];
#pragma unroll
        for (int j = 0; j < 8; ++j) {
            const int d = kt * 32 + kg * 8 + j;          // < 128 always
            const int i = ct * 16 + col;
            const float f = (i < din)
                ? post_w[((size_t)k * COUT_D + d) * din + i] : 0.f;
            v[j] = f2bf(f);
        }
        unsigned short* o = dst + ((((size_t)k * NKT2 + kt) * NCT2 + ct) * 64 + lane) * 8;
        *(ushort4*)(o)     = make_ushort4(v[0], v[1], v[2], v[3]);
        *(ushort4*)(o + 4) = make_ushort4(v[4], v[5], v[6], v[7]);
    }
}

__global__ __launch_bounds__(256) void bs_main(
    const float* __restrict__ x,        // (B,2,T,F)
    const unsigned short* __restrict__ pre_wP,
    const float* __restrict__ pre_b,    // (K,128)
    const unsigned short* __restrict__ post_wP,
    const float* __restrict__ post_b,   // (K,din)
    const int*   __restrict__ idx,      // (K,W)
    const float* __restrict__ melw,     // (K,W)
    const float* __restrict__ mask,     // (K,W)
    const float* __restrict__ ola,      // (F)
    float* __restrict__ out,            // (B,2,T,F) pre-zeroed
    int W, int din)
{
    __shared__ unsigned short s_g[M_TILE][SG_LD];
    __shared__ unsigned short s_z[M_TILE][SZ_LD];
    __shared__ int   s_idx[WPAD];
    __shared__ float s_wt[WPAD];   // melw*mask (gather weight)
    __shared__ float s_sc[WPAD];   // (wt!=0) ? 1/ola[f] : 0

    const int k      = blockIdx.x;
    const int m_base = blockIdx.y * M_TILE;
    const int tid    = threadIdx.x;

    if (tid < WPAD) {
        const int wi = tid;
        int   fv = F_DIM - 1;
        float mw = 0.f;
        if (wi < W) {
            fv = idx[k * W + wi];
            mw = melw[k * W + wi] * mask[k * W + wi];
        }
        s_idx[wi] = fv;
        s_wt[wi]  = mw;
        s_sc[wi]  = (mw != 0.f) ? (1.0f / ola[fv]) : 0.f;
    }
    __syncthreads();

    // ---- gather: band bins are contiguous -> coalesced reads, bf16 to LDS
    {
        const int f0 = s_idx[0];
        for (int p = tid; p < M_TILE * 2 * WPAD; p += 256) {
            const int row = p / (2 * WPAD);
            const int rem = p - row * (2 * WPAD);
            const int c   = rem / WPAD;
            const int wi  = rem - c * WPAD;
            const int m   = m_base + row;
            const int b   = m >> 10;
            const int t   = m & 1023;
            int f = f0 + wi; if (f > F_DIM - 1) f = F_DIM - 1;
            const float v = x[((size_t)(b * 2 + c) * T_DIM + t) * F_DIM + f] * s_wt[wi];
            s_g[row][2 * wi + c] = f2bf(v);
        }
    }
    __syncthreads();

    const int lane = tid & 63;
    const int wave = tid >> 6;
    const int col  = lane & 15;
    const int kg   = lane >> 4;
    const int r0   = wave * 16;

    // ---- GEMM1: z[m][o] = g[m][:] . pre_w[:][o] + pre_b
    {
        f32x4 acc[NCT1];
#pragma unroll
        for (int ct = 0; ct < NCT1; ++ct) {
            const float bv = pre_b[k * COUT_D + ct * 16 + col];
            acc[ct] = (f32x4){bv, bv, bv, bv};
        }
        for (int kt = 0; kt < NKT1; ++kt) {
            const bf16x8 a = *(const bf16x8*)&s_g[r0 + col][kt * 32 + kg * 8];
            const bf16x8* bp = (const bf16x8*)(pre_wP
                + ((((size_t)k * NKT1 + kt) * NCT1) * 64 + lane) * 8);
#pragma unroll
            for (int ct = 0; ct < NCT1; ++ct) {
                acc[ct] = __builtin_amdgcn_mfma_f32_16x16x32_bf16(
                    a, bp[(size_t)ct * 64], acc[ct], 0, 0, 0);
            }
        }
#pragma unroll
        for (int ct = 0; ct < NCT1; ++ct)
#pragma unroll
            for (int reg = 0; reg < 4; ++reg)
                s_z[r0 + kg * 4 + reg][ct * 16 + col] = f2bf(acc[ct][reg]);
        // no barrier: each wave writes & reads only its own 16 rows of s_z
    }

    // ---- GEMM2: y[m][i] = z[m][:] . post_w[:][i]; fused scatter epilogue
    {
        f32x4 acc2[NCT2];
#pragma unroll
        for (int ct = 0; ct < NCT2; ++ct) acc2[ct] = (f32x4){0.f, 0.f, 0.f, 0.f};

        for (int kt = 0; kt < NKT2; ++kt) {
            const bf16x8 a = *(const bf16x8*)&s_z[r0 + col][kt * 32 + kg * 8];
            const bf16x8* bp = (const bf16x8*)(post_wP
                + ((((size_t)k * NKT2 + kt) * NCT2) * 64 + lane) * 8);
#pragma unroll
            for (int ct = 0; ct < NCT2; ++ct) {
                acc2[ct] = __builtin_amdgcn_mfma_f32_16x16x32_bf16(
                    a, bp[(size_t)ct * 64], acc2[ct], 0, 0, 0);
            }
        }

#pragma unroll
        for (int ct = 0; ct < NCT2; ++ct) {
            const int i  = ct * 16 + col;
            const int wi = i >> 1;
            const float sc = s_sc[wi];
            if (sc == 0.f) continue;                 // masked or pad column
            const int ch = i & 1;
            const int f  = s_idx[wi];
            const float pb = post_b[k * din + i];
#pragma unroll
            for (int reg = 0; reg < 4; ++reg) {
                const int m = m_base + r0 + kg * 4 + reg;
                const int b = m >> 10;
                const int t = m & 1023;
                atomicAdd(out + ((size_t)(b * 2 + ch) * T_DIM + t) * F_DIM + f,
                          (acc2[ct][reg] + pb) * sc);
            }
        }
    }
}

extern "C" void kernel_launch(void* const* d_in, const int* in_sizes, int n_in,
                              void* d_out, int out_size, void* d_ws, size_t ws_size,
                              hipStream_t stream) {
    const float* x      = (const float*)d_in[0];
    const float* pre_w  = (const float*)d_in[1];
    const float* pre_b  = (const float*)d_in[2];
    const float* post_w = (const float*)d_in[3];
    const float* post_b = (const float*)d_in[4];
    const int*   idx    = (const int*)d_in[5];
    const float* melw   = (const float*)d_in[6];
    const float* mask   = (const float*)d_in[7];
    const float* ola    = (const float*)d_in[8];
    float* out = (float*)d_out;

    const int W   = in_sizes[5] / K_BANDS;   // ~106, must be <= WPAD
    const int din = 2 * W;

    unsigned short* pre_wP  = (unsigned short*)d_ws;
    const size_t pre_bytes  = (size_t)K_BANDS * NKT1 * NCT1 * 64 * 8 * 2;  // 3.67 MB
    unsigned short* post_wP = (unsigned short*)((char*)d_ws + pre_bytes);

    hipMemsetAsync(d_out, 0, (size_t)out_size * sizeof(float), stream);

    bs_pack_pre <<<dim3(K_BANDS, NKT1), 256, 0, stream>>>(pre_w,  pre_wP,  din);
    bs_pack_post<<<dim3(K_BANDS, NKT2), 256, 0, stream>>>(post_w, post_wP, din);

    dim3 grid(K_BANDS, (B_DIM * T_DIM) / M_TILE);
    bs_main<<<grid, 256, 0, stream>>>(x, pre_wP, pre_b, post_wP, post_b,
                                      idx, melw, mask, ola, out, W, din);
}

// Round 3
// 206.841 us; speedup vs baseline: 6.7961x; 1.0968x over previous
//
#include <hip/hip_runtime.h>

// BandSplit via bf16 MFMA. R3: melw/mask/(1/ola) folded into packed weights
// (gather = pure copy, epilogue = add-bias + atomic), vectorized gather,
// s_z unioned into s_g (LDS ~30 KB -> 5 blocks/CU).

#define K_BANDS 64
#define COUT_D  128
#define T_DIM   1024
#define B_DIM   4
#define F_DIM   1025
#define M_TILE  64
#define WPAD    112      // padded band width (actual W <= 112, verified R2)
#define DINP    224      // 2*WPAD, physical din, channel-blocked: i = c*112+wi
#define SG_LD   232      // s_g row stride (shorts); 116 dw % 32 = 20 -> spread
#define SZ_LD   136      // s_z row stride (shorts); 68 dw % 32 = 4 -> spread
#define NKT1    7
#define NKT2    4
#define NCT1    8
#define NCT2    14

typedef __attribute__((ext_vector_type(8))) short bf16x8;
typedef __attribute__((ext_vector_type(4))) float f32x4;

__device__ __forceinline__ unsigned short f2bf(float f) {
    unsigned u = __builtin_bit_cast(unsigned, f);
    u += 0x7FFFu + ((u >> 16) & 1u);          // RNE
    return (unsigned short)(u >> 16);
}

struct alignas(4) f4u { float v[4]; };        // 4B-aligned 16B load

// ---- pack pre_w: (K,din,128) f32 -> frag order (k,kt,ct,lane,8) bf16, * wt(i)
__global__ __launch_bounds__(256) void bs_pack_pre(
    const float* __restrict__ pre_w, const float* __restrict__ melw,
    const float* __restrict__ mask, unsigned short* __restrict__ dst,
    int W, int din)
{
    const int k = blockIdx.x, kt = blockIdx.y;
    for (int q = threadIdx.x; q < NCT1 * 64; q += 256) {
        const int ct = q >> 6, lane = q & 63;
        const int col = lane & 15, kg = lane >> 4;
        unsigned short v[8];
#pragma unroll
        for (int j = 0; j < 8; ++j) {
            const int i  = kt * 32 + kg * 8 + j;
            const int cc = (i >= WPAD);
            const int wi = i - cc * WPAD;
            float f = 0.f;
            if (wi < W) {
                const float wt = melw[k * W + wi] * mask[k * W + wi];
                f = wt * pre_w[((size_t)k * din + 2 * wi + cc) * COUT_D + ct * 16 + col];
            }
            v[j] = f2bf(f);
        }
        unsigned short* o = dst + ((((size_t)k * NKT1 + kt) * NCT1 + ct) * 64 + lane) * 8;
        *(ushort4*)(o)     = make_ushort4(v[0], v[1], v[2], v[3]);
        *(ushort4*)(o + 4) = make_ushort4(v[4], v[5], v[6], v[7]);
    }
}

// ---- pack post_w: (K,128,din) -> frag order * sc(i);  post_b' = post_b * sc
__global__ __launch_bounds__(256) void bs_pack_post(
    const float* __restrict__ post_w, const float* __restrict__ post_b,
    const int* __restrict__ idx, const float* __restrict__ melw,
    const float* __restrict__ mask, const float* __restrict__ ola,
    unsigned short* __restrict__ dstW, float* __restrict__ dstB,
    int W, int din)
{
    const int k = blockIdx.x, kt = blockIdx.y;
    for (int q = threadIdx.x; q < NCT2 * 64; q += 256) {
        const int ct = q >> 6, lane = q & 63;
        const int col = lane & 15, kg = lane >> 4;
        const int i  = ct * 16 + col;
        const int cc = (i >= WPAD);
        const int wi = i - cc * WPAD;
        float sc = 0.f;
        if (wi < W) {
            const float mw = melw[k * W + wi] * mask[k * W + wi];
            if (mw != 0.f) sc = 1.0f / ola[idx[k * W + wi]];
        }
        unsigned short v[8];
#pragma unroll
        for (int j = 0; j < 8; ++j) {
            const int d = kt * 32 + kg * 8 + j;
            const float f = (wi < W)
                ? sc * post_w[((size_t)k * COUT_D + d) * din + 2 * wi + cc] : 0.f;
            v[j] = f2bf(f);
        }
        unsigned short* o = dstW + ((((size_t)k * NKT2 + kt) * NCT2 + ct) * 64 + lane) * 8;
        *(ushort4*)(o)     = make_ushort4(v[0], v[1], v[2], v[3]);
        *(ushort4*)(o + 4) = make_ushort4(v[4], v[5], v[6], v[7]);
    }
    if (kt == 0) {
        for (int i = threadIdx.x; i < DINP; i += 256) {
            const int cc = (i >= WPAD);
            const int wi = i - cc * WPAD;
            float pb = 0.f;
            if (wi < W) {
                const float mw = melw[k * W + wi] * mask[k * W + wi];
                if (mw != 0.f)
                    pb = post_b[k * din + 2 * wi + cc] / ola[idx[k * W + wi]];
            }
            dstB[k * DINP + i] = pb;
        }
    }
}

__global__ __launch_bounds__(256) void bs_main(
    const float* __restrict__ x,        // (B,2,T,F)
    const unsigned short* __restrict__ pre_wP,
    const float* __restrict__ pre_b,    // (K,128)
    const unsigned short* __restrict__ post_wP,
    const float* __restrict__ post_bP,  // (K,DINP), scaled
    const int*   __restrict__ idx,      // (K,W)
    const float* __restrict__ melw,
    const float* __restrict__ mask,
    float* __restrict__ out,            // pre-zeroed
    int W)
{
    __shared__ unsigned short s_raw[M_TILE * SG_LD];   // union: g / z
    __shared__ float s_sc[WPAD];                       // skip flags

    auto g = (unsigned short (*)[SG_LD])s_raw;
    auto z = (unsigned short (*)[SZ_LD])s_raw;

    const int k      = blockIdx.x;
    const int m_base = blockIdx.y * M_TILE;
    const int tid    = threadIdx.x;
    const int f0     = idx[(size_t)k * W];             // contiguous band bins

    if (tid < WPAD) {
        float flg = 0.f;
        if (tid < W) flg = (melw[k * W + tid] * mask[k * W + tid] != 0.f) ? 1.f : 0.f;
        s_sc[tid] = flg;
    }

    // ---- gather: pure copy x -> bf16 LDS, dwordx4 via align-down
    {
        const size_t x_total = (size_t)B_DIM * 2 * T_DIM * F_DIM;
        for (int p = tid; p < 128 * 32; p += 256) {
            const int seg = p >> 5;       // row*2 + c
            const int q   = p & 31;
            if (q >= 29) continue;
            const int row = seg >> 1;
            const int c   = seg & 1;
            const int m   = m_base + row;
            const int b   = m >> 10;
            const int t   = m & 1023;
            const size_t base = ((size_t)(b * 2 + c) * T_DIM + t) * F_DIM + f0;
            const size_t a0   = base & ~(size_t)3;
            const int    off  = (int)(base - a0);
            size_t addr = a0 + 4 * (size_t)q;
            if (addr + 4 > x_total) addr = x_total - 4;   // clamped values unused
            const f4u vv = *reinterpret_cast<const f4u*>(x + addr);
#pragma unroll
            for (int e = 0; e < 4; ++e) {
                const int wi = 4 * q + e - off;
                if ((unsigned)wi < (unsigned)WPAD) {
                    const float val = (wi < W) ? vv.v[e] : 0.f;
                    g[row][c * WPAD + wi] = f2bf(val);
                }
            }
        }
    }
    __syncthreads();

    const int lane = tid & 63;
    const int wave = tid >> 6;
    const int col  = lane & 15;
    const int kg   = lane >> 4;
    const int r0   = wave * 16;

    // ---- GEMM1: z = g . pre_w' + pre_b
    f32x4 acc[NCT1];
#pragma unroll
    for (int ct = 0; ct < NCT1; ++ct) {
        const float bv = pre_b[k * COUT_D + ct * 16 + col];
        acc[ct] = (f32x4){bv, bv, bv, bv};
    }
    for (int kt = 0; kt < NKT1; ++kt) {
        const bf16x8 a = *(const bf16x8*)&g[r0 + col][kt * 32 + kg * 8];
        const bf16x8* bp = (const bf16x8*)(pre_wP
            + ((((size_t)k * NKT1 + kt) * NCT1) * 64 + lane) * 8);
#pragma unroll
        for (int ct = 0; ct < NCT1; ++ct)
            acc[ct] = __builtin_amdgcn_mfma_f32_16x16x32_bf16(
                a, bp[(size_t)ct * 64], acc[ct], 0, 0, 0);
    }
    __syncthreads();   // all g-reads done before z overwrites the union

#pragma unroll
    for (int ct = 0; ct < NCT1; ++ct)
#pragma unroll
        for (int reg = 0; reg < 4; ++reg)
            z[r0 + kg * 4 + reg][ct * 16 + col] = f2bf(acc[ct][reg]);
    // each wave reads only its own 16 z-rows -> no barrier

    // ---- GEMM2: y = z . post_w'  (mask & 1/ola already folded)
    f32x4 acc2[NCT2];
#pragma unroll
    for (int ct = 0; ct < NCT2; ++ct) acc2[ct] = (f32x4){0.f, 0.f, 0.f, 0.f};
    for (int kt = 0; kt < NKT2; ++kt) {
        const bf16x8 a = *(const bf16x8*)&z[r0 + col][kt * 32 + kg * 8];
        const bf16x8* bp = (const bf16x8*)(post_wP
            + ((((size_t)k * NKT2 + kt) * NCT2) * 64 + lane) * 8);
#pragma unroll
        for (int ct = 0; ct < NCT2; ++ct)
            acc2[ct] = __builtin_amdgcn_mfma_f32_16x16x32_bf16(
                a, bp[(size_t)ct * 64], acc2[ct], 0, 0, 0);
    }

    // ---- epilogue: atomic scatter, bias pre-scaled
    size_t obase[4][2];
#pragma unroll
    for (int reg = 0; reg < 4; ++reg) {
        const int m = m_base + r0 + kg * 4 + reg;
        const int b = m >> 10;
        const int t = m & 1023;
        obase[reg][0] = ((size_t)(b * 2) * T_DIM + t) * F_DIM + f0;
        obase[reg][1] = obase[reg][0] + (size_t)T_DIM * F_DIM;
    }
#pragma unroll
    for (int ct = 0; ct < NCT2; ++ct) {
        const int i  = ct * 16 + col;
        const int cc = (i >= WPAD);
        const int wi = i - cc * WPAD;
        if (s_sc[wi] == 0.f) continue;
        const float pb = post_bP[k * DINP + i];
#pragma unroll
        for (int reg = 0; reg < 4; ++reg)
            atomicAdd(out + obase[reg][cc] + wi, acc2[ct][reg] + pb);
    }
}

extern "C" void kernel_launch(void* const* d_in, const int* in_sizes, int n_in,
                              void* d_out, int out_size, void* d_ws, size_t ws_size,
                              hipStream_t stream) {
    const float* x      = (const float*)d_in[0];
    const float* pre_w  = (const float*)d_in[1];
    const float* pre_b  = (const float*)d_in[2];
    const float* post_w = (const float*)d_in[3];
    const float* post_b = (const float*)d_in[4];
    const int*   idx    = (const int*)d_in[5];
    const float* melw   = (const float*)d_in[6];
    const float* mask   = (const float*)d_in[7];
    const float* ola    = (const float*)d_in[8];
    float* out = (float*)d_out;

    const int W   = in_sizes[5] / K_BANDS;
    const int din = 2 * W;

    unsigned short* pre_wP  = (unsigned short*)d_ws;
    const size_t pre_bytes  = (size_t)K_BANDS * NKT1 * NCT1 * 64 * 8 * 2;
    unsigned short* post_wP = (unsigned short*)((char*)d_ws + pre_bytes);
    const size_t post_bytes = (size_t)K_BANDS * NKT2 * NCT2 * 64 * 8 * 2;
    float* post_bP = (float*)((char*)d_ws + pre_bytes + post_bytes);

    hipMemsetAsync(d_out, 0, (size_t)out_size * sizeof(float), stream);

    bs_pack_pre <<<dim3(K_BANDS, NKT1), 256, 0, stream>>>(pre_w, melw, mask,
                                                          pre_wP, W, din);
    bs_pack_post<<<dim3(K_BANDS, NKT2), 256, 0, stream>>>(post_w, post_b, idx,
                                                          melw, mask, ola,
                                                          post_wP, post_bP, W, din);

    dim3 grid(K_BANDS, (B_DIM * T_DIM) / M_TILE);
    bs_main<<<grid, 256, 0, stream>>>(x, pre_wP, pre_b, post_wP, post_bP,
                                      idx, melw, mask, out, W);
}

// Round 5
// 171.430 us; speedup vs baseline: 8.2000x; 1.2066x over previous
//
#include <hip/hip_runtime.h>

// BandSplit via bf16 MFMA. R5 = R4 (column-split waves, 4:1 MFMA:B-load,
// reg double-buffered B) + fixed gather tail: in-bounds chunks use dwordx4,
// the array-end chunk uses per-element clamped loads (correct for wi<W).

#define K_BANDS 64
#define COUT_D  128
#define T_DIM   1024
#define B_DIM   4
#define F_DIM   1025
#define M_TILE  64
#define WPAD    112      // padded band width (actual W <= 112)
#define DINP    224      // 2*WPAD, channel-blocked: i = c*WPAD + wi
#define SG_LD   232      // s_g row stride (shorts); 116 dw % 32 = 20 -> spread
#define SZ_LD   136      // s_z row stride (shorts); 68 dw % 32 = 4 -> spread
#define NKT1    7
#define NKT2    4
#define NCT1    8
#define NCT2    14

typedef __attribute__((ext_vector_type(8))) short bf16x8;
typedef __attribute__((ext_vector_type(4))) float f32x4;

__device__ __forceinline__ unsigned short f2bf(float f) {
    unsigned u = __builtin_bit_cast(unsigned, f);
    u += 0x7FFFu + ((u >> 16) & 1u);          // RNE
    return (unsigned short)(u >> 16);
}

struct alignas(4) f4u { float v[4]; };        // dword-aligned 16B load

// ---- pack pre_w: (K,din,128) f32 -> frag order (k,kt,ct,lane,8) bf16, * wt(i)
__global__ __launch_bounds__(256) void bs_pack_pre(
    const float* __restrict__ pre_w, const float* __restrict__ melw,
    const float* __restrict__ mask, unsigned short* __restrict__ dst,
    int W, int din)
{
    const int k = blockIdx.x, kt = blockIdx.y;
    for (int q = threadIdx.x; q < NCT1 * 64; q += 256) {
        const int ct = q >> 6, lane = q & 63;
        const int col = lane & 15, kg = lane >> 4;
        unsigned short v[8];
#pragma unroll
        for (int j = 0; j < 8; ++j) {
            const int i  = kt * 32 + kg * 8 + j;
            const int cc = (i >= WPAD);
            const int wi = i - cc * WPAD;
            float f = 0.f;
            if (wi < W) {
                const float wt = melw[k * W + wi] * mask[k * W + wi];
                f = wt * pre_w[((size_t)k * din + 2 * wi + cc) * COUT_D + ct * 16 + col];
            }
            v[j] = f2bf(f);
        }
        unsigned short* o = dst + ((((size_t)k * NKT1 + kt) * NCT1 + ct) * 64 + lane) * 8;
        *(ushort4*)(o)     = make_ushort4(v[0], v[1], v[2], v[3]);
        *(ushort4*)(o + 4) = make_ushort4(v[4], v[5], v[6], v[7]);
    }
}

// ---- pack post_w: (K,128,din) -> frag order * sc(i);  post_b' = post_b * sc
__global__ __launch_bounds__(256) void bs_pack_post(
    const float* __restrict__ post_w, const float* __restrict__ post_b,
    const int* __restrict__ idx, const float* __restrict__ melw,
    const float* __restrict__ mask, const float* __restrict__ ola,
    unsigned short* __restrict__ dstW, float* __restrict__ dstB,
    int W, int din)
{
    const int k = blockIdx.x, kt = blockIdx.y;
    for (int q = threadIdx.x; q < NCT2 * 64; q += 256) {
        const int ct = q >> 6, lane = q & 63;
        const int col = lane & 15, kg = lane >> 4;
        const int i  = ct * 16 + col;
        const int cc = (i >= WPAD);
        const int wi = i - cc * WPAD;
        float sc = 0.f;
        if (wi < W) {
            const float mw = melw[k * W + wi] * mask[k * W + wi];
            if (mw != 0.f) sc = 1.0f / ola[idx[k * W + wi]];
        }
        unsigned short v[8];
#pragma unroll
        for (int j = 0; j < 8; ++j) {
            const int d = kt * 32 + kg * 8 + j;
            const float f = (wi < W)
                ? sc * post_w[((size_t)k * COUT_D + d) * din + 2 * wi + cc] : 0.f;
            v[j] = f2bf(f);
        }
        unsigned short* o = dstW + ((((size_t)k * NKT2 + kt) * NCT2 + ct) * 64 + lane) * 8;
        *(ushort4*)(o)     = make_ushort4(v[0], v[1], v[2], v[3]);
        *(ushort4*)(o + 4) = make_ushort4(v[4], v[5], v[6], v[7]);
    }
    if (kt == 0) {
        for (int i = threadIdx.x; i < DINP; i += 256) {
            const int cc = (i >= WPAD);
            const int wi = i - cc * WPAD;
            float pb = 0.f;
            if (wi < W) {
                const float mw = melw[k * W + wi] * mask[k * W + wi];
                if (mw != 0.f)
                    pb = post_b[k * din + 2 * wi + cc] / ola[idx[k * W + wi]];
            }
            dstB[k * DINP + i] = pb;
        }
    }
}

__global__ __launch_bounds__(256) void bs_main(
    const float* __restrict__ x,        // (B,2,T,F)
    const unsigned short* __restrict__ pre_wP,
    const float* __restrict__ pre_b,    // (K,128)
    const unsigned short* __restrict__ post_wP,
    const float* __restrict__ post_bP,  // (K,DINP), scaled
    const int*   __restrict__ idx,      // (K,W)
    const float* __restrict__ melw,
    const float* __restrict__ mask,
    float* __restrict__ out,            // pre-zeroed
    int W)
{
    __shared__ unsigned short s_raw[M_TILE * SG_LD];   // union: g / z
    __shared__ float s_sc[WPAD];                       // skip flags

    auto g = (unsigned short (*)[SG_LD])s_raw;
    auto z = (unsigned short (*)[SZ_LD])s_raw;

    const int k      = blockIdx.x;
    const int m_base = blockIdx.y * M_TILE;
    const int tid    = threadIdx.x;
    const int f0     = idx[(size_t)k * W];             // band bins contiguous

    if (tid < WPAD) {
        float flg = 0.f;
        if (tid < W) flg = (melw[k * W + tid] * mask[k * W + tid] != 0.f) ? 1.f : 0.f;
        s_sc[tid] = flg;
    }

    // ---- gather: exact-offset dwordx4 loads; array-end chunk -> per-element
    // clamped loads (correct for all wi < W; wi >= W killed by zero weights).
    {
        const size_t x_total = (size_t)B_DIM * 2 * T_DIM * F_DIM;
        for (int p = tid; p < M_TILE * 2 * 28; p += 256) {
            const int seg = p / 28;          // row*2 + c
            const int q   = p - seg * 28;    // 4-dword chunk within band
            const int row = seg >> 1;
            const int c   = seg & 1;
            const int m   = m_base + row;
            const int b   = m >> 10;
            const int t   = m & 1023;
            const size_t addr = ((size_t)(b * 2 + c) * T_DIM + t) * F_DIM + f0
                                + 4 * (size_t)q;
            float v0, v1, v2, v3;
            if (addr + 4 <= x_total) {
                const f4u vv = *reinterpret_cast<const f4u*>(x + addr);
                v0 = vv.v[0]; v1 = vv.v[1]; v2 = vv.v[2]; v3 = vv.v[3];
            } else {                         // only the last row of x ever hits
                const size_t last = x_total - 1;
                v0 = x[addr     < last ? addr     : last];
                v1 = x[addr + 1 < last ? addr + 1 : last];
                v2 = x[addr + 2 < last ? addr + 2 : last];
                v3 = x[addr + 3 < last ? addr + 3 : last];
            }
            const unsigned lo = (unsigned)f2bf(v0) | ((unsigned)f2bf(v1) << 16);
            const unsigned hi = (unsigned)f2bf(v2) | ((unsigned)f2bf(v3) << 16);
            unsigned* dstw = (unsigned*)&g[row][c * WPAD + 4 * q];
            dstw[0] = lo;
            dstw[1] = hi;
        }
    }
    __syncthreads();

    const int lane = tid & 63;
    const int wave = tid >> 6;
    const int col  = lane & 15;
    const int kg   = lane >> 4;

    // ---- GEMM1: z = g . pre_w' + pre_b.  Wave w owns ct = {2w, 2w+1}.
    f32x4 acc1[2][4];                       // [ctl][mf]
#pragma unroll
    for (int ctl = 0; ctl < 2; ++ctl) {
        const float bv = pre_b[k * COUT_D + (2 * wave + ctl) * 16 + col];
#pragma unroll
        for (int mf = 0; mf < 4; ++mf) acc1[ctl][mf] = (f32x4){bv, bv, bv, bv};
    }
    {
        const bf16x8* bp = (const bf16x8*)(pre_wP + (size_t)k * NKT1 * NCT1 * 64 * 8);
        bf16x8 bnx[2];
#pragma unroll
        for (int ctl = 0; ctl < 2; ++ctl)
            bnx[ctl] = bp[(size_t)(0 * NCT1 + 2 * wave + ctl) * 64 + lane];
        for (int kt = 0; kt < NKT1; ++kt) {
            bf16x8 bc[2];
#pragma unroll
            for (int ctl = 0; ctl < 2; ++ctl) bc[ctl] = bnx[ctl];
            if (kt + 1 < NKT1) {
#pragma unroll
                for (int ctl = 0; ctl < 2; ++ctl)
                    bnx[ctl] = bp[(size_t)((kt + 1) * NCT1 + 2 * wave + ctl) * 64 + lane];
            }
            bf16x8 a[4];
#pragma unroll
            for (int mf = 0; mf < 4; ++mf)
                a[mf] = *(const bf16x8*)&g[mf * 16 + col][kt * 32 + kg * 8];
#pragma unroll
            for (int ctl = 0; ctl < 2; ++ctl)
#pragma unroll
                for (int mf = 0; mf < 4; ++mf)
                    acc1[ctl][mf] = __builtin_amdgcn_mfma_f32_16x16x32_bf16(
                        a[mf], bc[ctl], acc1[ctl][mf], 0, 0, 0);
        }
    }
    __syncthreads();   // all g-reads complete before z overwrites the union

#pragma unroll
    for (int ctl = 0; ctl < 2; ++ctl) {
        const int ct = 2 * wave + ctl;
#pragma unroll
        for (int mf = 0; mf < 4; ++mf)
#pragma unroll
            for (int reg = 0; reg < 4; ++reg)
                z[mf * 16 + kg * 4 + reg][ct * 16 + col] = f2bf(acc1[ctl][mf][reg]);
    }
    __syncthreads();   // z complete before cross-wave reads

    // ---- GEMM2: y = z . post_w'.  Wave w owns ct = {w, w+4, w+8, w+12}.
    f32x4 acc2[4][4];                       // [j][mf]
#pragma unroll
    for (int j = 0; j < 4; ++j)
#pragma unroll
        for (int mf = 0; mf < 4; ++mf) acc2[j][mf] = (f32x4){0.f, 0.f, 0.f, 0.f};
    {
        const bf16x8* bp = (const bf16x8*)(post_wP + (size_t)k * NKT2 * NCT2 * 64 * 8);
        bf16x8 bnx[4];
#pragma unroll
        for (int j = 0; j < 4; ++j) {
            const int ct = wave + 4 * j;
            if (ct < NCT2) bnx[j] = bp[(size_t)(0 * NCT2 + ct) * 64 + lane];
        }
        for (int kt = 0; kt < NKT2; ++kt) {
            bf16x8 bc[4];
#pragma unroll
            for (int j = 0; j < 4; ++j) bc[j] = bnx[j];
            if (kt + 1 < NKT2) {
#pragma unroll
                for (int j = 0; j < 4; ++j) {
                    const int ct = wave + 4 * j;
                    if (ct < NCT2)
                        bnx[j] = bp[(size_t)((kt + 1) * NCT2 + ct) * 64 + lane];
                }
            }
            bf16x8 a[4];
#pragma unroll
            for (int mf = 0; mf < 4; ++mf)
                a[mf] = *(const bf16x8*)&z[mf * 16 + col][kt * 32 + kg * 8];
#pragma unroll
            for (int j = 0; j < 4; ++j) {
                if (wave + 4 * j < NCT2) {
#pragma unroll
                    for (int mf = 0; mf < 4; ++mf)
                        acc2[j][mf] = __builtin_amdgcn_mfma_f32_16x16x32_bf16(
                            a[mf], bc[j], acc2[j][mf], 0, 0, 0);
                }
            }
        }
    }

    // ---- epilogue: atomic scatter (bias & 1/ola & mask pre-folded)
    {
        const int    b  = m_base >> 10;          // 64 | 1024 -> tile in one b
        const int    t0 = m_base & 1023;
        const size_t rb0 = ((size_t)(b * 2 + 0) * T_DIM + t0) * F_DIM + f0;
        const size_t rb1 = rb0 + (size_t)T_DIM * F_DIM;
#pragma unroll
        for (int j = 0; j < 4; ++j) {
            const int ct = wave + 4 * j;
            if (ct >= NCT2) continue;
            const int i  = ct * 16 + col;
            const int cc = (i >= WPAD);
            const int wi = i - cc * WPAD;
            if (s_sc[wi] == 0.f) continue;
            const float  pb   = post_bP[k * DINP + i];
            const size_t base = (cc ? rb1 : rb0) + wi;
#pragma unroll
            for (int mf = 0; mf < 4; ++mf)
#pragma unroll
                for (int reg = 0; reg < 4; ++reg) {
                    const int r = mf * 16 + kg * 4 + reg;
                    atomicAdd(out + base + (size_t)r * F_DIM,
                              acc2[j][mf][reg] + pb);
                }
        }
    }
}

extern "C" void kernel_launch(void* const* d_in, const int* in_sizes, int n_in,
                              void* d_out, int out_size, void* d_ws, size_t ws_size,
                              hipStream_t stream) {
    const float* x      = (const float*)d_in[0];
    const float* pre_w  = (const float*)d_in[1];
    const float* pre_b  = (const float*)d_in[2];
    const float* post_w = (const float*)d_in[3];
    const float* post_b = (const float*)d_in[4];
    const int*   idx    = (const int*)d_in[5];
    const float* melw   = (const float*)d_in[6];
    const float* mask   = (const float*)d_in[7];
    const float* ola    = (const float*)d_in[8];
    float* out = (float*)d_out;

    const int W   = in_sizes[5] / K_BANDS;
    const int din = 2 * W;

    unsigned short* pre_wP  = (unsigned short*)d_ws;
    const size_t pre_bytes  = (size_t)K_BANDS * NKT1 * NCT1 * 64 * 8 * 2;
    unsigned short* post_wP = (unsigned short*)((char*)d_ws + pre_bytes);
    const size_t post_bytes = (size_t)K_BANDS * NKT2 * NCT2 * 64 * 8 * 2;
    float* post_bP = (float*)((char*)d_ws + pre_bytes + post_bytes);

    hipMemsetAsync(d_out, 0, (size_t)out_size * sizeof(float), stream);

    bs_pack_pre <<<dim3(K_BANDS, NKT1), 256, 0, stream>>>(pre_w, melw, mask,
                                                          pre_wP, W, din);
    bs_pack_post<<<dim3(K_BANDS, NKT2), 256, 0, stream>>>(post_w, post_b, idx,
                                                          melw, mask, ola,
                                                          post_wP, post_bP, W, din);

    dim3 grid(K_BANDS, (B_DIM * T_DIM) / M_TILE);
    bs_main<<<grid, 256, 0, stream>>>(x, pre_wP, pre_b, post_wP, post_bP,
                                      idx, melw, mask, out, W);
}

// Round 6
// 160.859 us; speedup vs baseline: 8.7389x; 1.0657x over previous
//
#include <hip/hip_runtime.h>

// BandSplit via bf16 MFMA. R6: atomic-free scatter via band parity.
// Even-band supports are mutually disjoint in f (mel triangles overlap only
// adjacent bands), likewise odd. Kernel<0> (even bands) does plain stores;
// kernel<1> (odd bands) does read-add-store, ordered after it on the stream.
// Rest identical to R5: column-split waves, 4:1 MFMA:B-load, folded scales.

#define K_BANDS 64
#define COUT_D  128
#define T_DIM   1024
#define B_DIM   4
#define F_DIM   1025
#define M_TILE  64
#define WPAD    112      // padded band width (actual W <= 112)
#define DINP    224      // 2*WPAD, channel-blocked: i = c*WPAD + wi
#define SG_LD   232      // s_g row stride (shorts); 116 dw % 32 = 20 -> spread
#define SZ_LD   136      // s_z row stride (shorts); 68 dw % 32 = 4 -> spread
#define NKT1    7
#define NKT2    4
#define NCT1    8
#define NCT2    14

typedef __attribute__((ext_vector_type(8))) short bf16x8;
typedef __attribute__((ext_vector_type(4))) float f32x4;

__device__ __forceinline__ unsigned short f2bf(float f) {
    unsigned u = __builtin_bit_cast(unsigned, f);
    u += 0x7FFFu + ((u >> 16) & 1u);          // RNE
    return (unsigned short)(u >> 16);
}

struct alignas(4) f4u { float v[4]; };        // dword-aligned 16B load

// ---- pack pre_w: (K,din,128) f32 -> frag order (k,kt,ct,lane,8) bf16, * wt(i)
__global__ __launch_bounds__(256) void bs_pack_pre(
    const float* __restrict__ pre_w, const float* __restrict__ melw,
    const float* __restrict__ mask, unsigned short* __restrict__ dst,
    int W, int din)
{
    const int k = blockIdx.x, kt = blockIdx.y;
    for (int q = threadIdx.x; q < NCT1 * 64; q += 256) {
        const int ct = q >> 6, lane = q & 63;
        const int col = lane & 15, kg = lane >> 4;
        unsigned short v[8];
#pragma unroll
        for (int j = 0; j < 8; ++j) {
            const int i  = kt * 32 + kg * 8 + j;
            const int cc = (i >= WPAD);
            const int wi = i - cc * WPAD;
            float f = 0.f;
            if (wi < W) {
                const float wt = melw[k * W + wi] * mask[k * W + wi];
                f = wt * pre_w[((size_t)k * din + 2 * wi + cc) * COUT_D + ct * 16 + col];
            }
            v[j] = f2bf(f);
        }
        unsigned short* o = dst + ((((size_t)k * NKT1 + kt) * NCT1 + ct) * 64 + lane) * 8;
        *(ushort4*)(o)     = make_ushort4(v[0], v[1], v[2], v[3]);
        *(ushort4*)(o + 4) = make_ushort4(v[4], v[5], v[6], v[7]);
    }
}

// ---- pack post_w: (K,128,din) -> frag order * sc(i);  post_b' = post_b * sc
__global__ __launch_bounds__(256) void bs_pack_post(
    const float* __restrict__ post_w, const float* __restrict__ post_b,
    const int* __restrict__ idx, const float* __restrict__ melw,
    const float* __restrict__ mask, const float* __restrict__ ola,
    unsigned short* __restrict__ dstW, float* __restrict__ dstB,
    int W, int din)
{
    const int k = blockIdx.x, kt = blockIdx.y;
    for (int q = threadIdx.x; q < NCT2 * 64; q += 256) {
        const int ct = q >> 6, lane = q & 63;
        const int col = lane & 15, kg = lane >> 4;
        const int i  = ct * 16 + col;
        const int cc = (i >= WPAD);
        const int wi = i - cc * WPAD;
        float sc = 0.f;
        if (wi < W) {
            const float mw = melw[k * W + wi] * mask[k * W + wi];
            if (mw != 0.f) sc = 1.0f / ola[idx[k * W + wi]];
        }
        unsigned short v[8];
#pragma unroll
        for (int j = 0; j < 8; ++j) {
            const int d = kt * 32 + kg * 8 + j;
            const float f = (wi < W)
                ? sc * post_w[((size_t)k * COUT_D + d) * din + 2 * wi + cc] : 0.f;
            v[j] = f2bf(f);
        }
        unsigned short* o = dstW + ((((size_t)k * NKT2 + kt) * NCT2 + ct) * 64 + lane) * 8;
        *(ushort4*)(o)     = make_ushort4(v[0], v[1], v[2], v[3]);
        *(ushort4*)(o + 4) = make_ushort4(v[4], v[5], v[6], v[7]);
    }
    if (kt == 0) {
        for (int i = threadIdx.x; i < DINP; i += 256) {
            const int cc = (i >= WPAD);
            const int wi = i - cc * WPAD;
            float pb = 0.f;
            if (wi < W) {
                const float mw = melw[k * W + wi] * mask[k * W + wi];
                if (mw != 0.f)
                    pb = post_b[k * din + 2 * wi + cc] / ola[idx[k * W + wi]];
            }
            dstB[k * DINP + i] = pb;
        }
    }
}

template <int PARITY>
__global__ __launch_bounds__(256) void bs_main(
    const float* __restrict__ x,        // (B,2,T,F)
    const unsigned short* __restrict__ pre_wP,
    const float* __restrict__ pre_b,    // (K,128)
    const unsigned short* __restrict__ post_wP,
    const float* __restrict__ post_bP,  // (K,DINP), scaled
    const int*   __restrict__ idx,      // (K,W)
    const float* __restrict__ melw,
    const float* __restrict__ mask,
    float* __restrict__ out,            // pre-zeroed
    int W)
{
    __shared__ unsigned short s_raw[M_TILE * SG_LD];   // union: g / z
    __shared__ float s_sc[WPAD];                       // skip flags

    auto g = (unsigned short (*)[SG_LD])s_raw;
    auto z = (unsigned short (*)[SZ_LD])s_raw;

    const int k      = blockIdx.x * 2 + PARITY;        // same-parity bands:
    const int m_base = blockIdx.y * M_TILE;            // disjoint f-support
    const int tid    = threadIdx.x;
    const int f0     = idx[(size_t)k * W];             // band bins contiguous

    if (tid < WPAD) {
        float flg = 0.f;
        if (tid < W) flg = (melw[k * W + tid] * mask[k * W + tid] != 0.f) ? 1.f : 0.f;
        s_sc[tid] = flg;
    }

    // ---- gather: exact-offset dwordx4 loads; array-end chunk -> per-element
    // clamped loads (correct for all wi < W; wi >= W killed by zero weights).
    {
        const size_t x_total = (size_t)B_DIM * 2 * T_DIM * F_DIM;
        for (int p = tid; p < M_TILE * 2 * 28; p += 256) {
            const int seg = p / 28;          // row*2 + c
            const int q   = p - seg * 28;    // 4-dword chunk within band
            const int row = seg >> 1;
            const int c   = seg & 1;
            const int m   = m_base + row;
            const int b   = m >> 10;
            const int t   = m & 1023;
            const size_t addr = ((size_t)(b * 2 + c) * T_DIM + t) * F_DIM + f0
                                + 4 * (size_t)q;
            float v0, v1, v2, v3;
            if (addr + 4 <= x_total) {
                const f4u vv = *reinterpret_cast<const f4u*>(x + addr);
                v0 = vv.v[0]; v1 = vv.v[1]; v2 = vv.v[2]; v3 = vv.v[3];
            } else {                         // only the last row of x ever hits
                const size_t last = x_total - 1;
                v0 = x[addr     < last ? addr     : last];
                v1 = x[addr + 1 < last ? addr + 1 : last];
                v2 = x[addr + 2 < last ? addr + 2 : last];
                v3 = x[addr + 3 < last ? addr + 3 : last];
            }
            const unsigned lo = (unsigned)f2bf(v0) | ((unsigned)f2bf(v1) << 16);
            const unsigned hi = (unsigned)f2bf(v2) | ((unsigned)f2bf(v3) << 16);
            unsigned* dstw = (unsigned*)&g[row][c * WPAD + 4 * q];
            dstw[0] = lo;
            dstw[1] = hi;
        }
    }
    __syncthreads();

    const int lane = tid & 63;
    const int wave = tid >> 6;
    const int col  = lane & 15;
    const int kg   = lane >> 4;

    // ---- GEMM1: z = g . pre_w' + pre_b.  Wave w owns ct = {2w, 2w+1}.
    f32x4 acc1[2][4];                       // [ctl][mf]
#pragma unroll
    for (int ctl = 0; ctl < 2; ++ctl) {
        const float bv = pre_b[k * COUT_D + (2 * wave + ctl) * 16 + col];
#pragma unroll
        for (int mf = 0; mf < 4; ++mf) acc1[ctl][mf] = (f32x4){bv, bv, bv, bv};
    }
    {
        const bf16x8* bp = (const bf16x8*)(pre_wP + (size_t)k * NKT1 * NCT1 * 64 * 8);
        bf16x8 bnx[2];
#pragma unroll
        for (int ctl = 0; ctl < 2; ++ctl)
            bnx[ctl] = bp[(size_t)(0 * NCT1 + 2 * wave + ctl) * 64 + lane];
        for (int kt = 0; kt < NKT1; ++kt) {
            bf16x8 bc[2];
#pragma unroll
            for (int ctl = 0; ctl < 2; ++ctl) bc[ctl] = bnx[ctl];
            if (kt + 1 < NKT1) {
#pragma unroll
                for (int ctl = 0; ctl < 2; ++ctl)
                    bnx[ctl] = bp[(size_t)((kt + 1) * NCT1 + 2 * wave + ctl) * 64 + lane];
            }
            bf16x8 a[4];
#pragma unroll
            for (int mf = 0; mf < 4; ++mf)
                a[mf] = *(const bf16x8*)&g[mf * 16 + col][kt * 32 + kg * 8];
#pragma unroll
            for (int ctl = 0; ctl < 2; ++ctl)
#pragma unroll
                for (int mf = 0; mf < 4; ++mf)
                    acc1[ctl][mf] = __builtin_amdgcn_mfma_f32_16x16x32_bf16(
                        a[mf], bc[ctl], acc1[ctl][mf], 0, 0, 0);
        }
    }
    __syncthreads();   // all g-reads complete before z overwrites the union

#pragma unroll
    for (int ctl = 0; ctl < 2; ++ctl) {
        const int ct = 2 * wave + ctl;
#pragma unroll
        for (int mf = 0; mf < 4; ++mf)
#pragma unroll
            for (int reg = 0; reg < 4; ++reg)
                z[mf * 16 + kg * 4 + reg][ct * 16 + col] = f2bf(acc1[ctl][mf][reg]);
    }
    __syncthreads();   // z complete before cross-wave reads

    // ---- GEMM2: y = z . post_w'.  Wave w owns ct = {w, w+4, w+8, w+12}.
    f32x4 acc2[4][4];                       // [j][mf]
#pragma unroll
    for (int j = 0; j < 4; ++j)
#pragma unroll
        for (int mf = 0; mf < 4; ++mf) acc2[j][mf] = (f32x4){0.f, 0.f, 0.f, 0.f};
    {
        const bf16x8* bp = (const bf16x8*)(post_wP + (size_t)k * NKT2 * NCT2 * 64 * 8);
        bf16x8 bnx[4];
#pragma unroll
        for (int j = 0; j < 4; ++j) {
            const int ct = wave + 4 * j;
            if (ct < NCT2) bnx[j] = bp[(size_t)(0 * NCT2 + ct) * 64 + lane];
        }
        for (int kt = 0; kt < NKT2; ++kt) {
            bf16x8 bc[4];
#pragma unroll
            for (int j = 0; j < 4; ++j) bc[j] = bnx[j];
            if (kt + 1 < NKT2) {
#pragma unroll
                for (int j = 0; j < 4; ++j) {
                    const int ct = wave + 4 * j;
                    if (ct < NCT2)
                        bnx[j] = bp[(size_t)((kt + 1) * NCT2 + ct) * 64 + lane];
                }
            }
            bf16x8 a[4];
#pragma unroll
            for (int mf = 0; mf < 4; ++mf)
                a[mf] = *(const bf16x8*)&z[mf * 16 + col][kt * 32 + kg * 8];
#pragma unroll
            for (int j = 0; j < 4; ++j) {
                if (wave + 4 * j < NCT2) {
#pragma unroll
                    for (int mf = 0; mf < 4; ++mf)
                        acc2[j][mf] = __builtin_amdgcn_mfma_f32_16x16x32_bf16(
                            a[mf], bc[j], acc2[j][mf], 0, 0, 0);
                }
            }
        }
    }

    // ---- epilogue: parity-disjoint scatter, NO atomics.
    // PARITY 0: sole writer among even bands -> plain store.
    // PARITY 1: sole writer among odd bands, runs after even kernel -> RMW.
    {
        const int    b  = m_base >> 10;          // 64 | 1024 -> tile in one b
        const int    t0 = m_base & 1023;
        const size_t rb0 = ((size_t)(b * 2 + 0) * T_DIM + t0) * F_DIM + f0;
        const size_t rb1 = rb0 + (size_t)T_DIM * F_DIM;
#pragma unroll
        for (int j = 0; j < 4; ++j) {
            const int ct = wave + 4 * j;
            if (ct >= NCT2) continue;
            const int i  = ct * 16 + col;
            const int cc = (i >= WPAD);
            const int wi = i - cc * WPAD;
            if (s_sc[wi] == 0.f) continue;
            const float  pb   = post_bP[k * DINP + i];
            const size_t base = (cc ? rb1 : rb0) + wi;
#pragma unroll
            for (int mf = 0; mf < 4; ++mf)
#pragma unroll
                for (int reg = 0; reg < 4; ++reg) {
                    const int r = mf * 16 + kg * 4 + reg;
                    float* p = out + base + (size_t)r * F_DIM;
                    const float v = acc2[j][mf][reg] + pb;
                    if (PARITY == 0) *p = v;
                    else             *p = *p + v;
                }
        }
    }
}

extern "C" void kernel_launch(void* const* d_in, const int* in_sizes, int n_in,
                              void* d_out, int out_size, void* d_ws, size_t ws_size,
                              hipStream_t stream) {
    const float* x      = (const float*)d_in[0];
    const float* pre_w  = (const float*)d_in[1];
    const float* pre_b  = (const float*)d_in[2];
    const float* post_w = (const float*)d_in[3];
    const float* post_b = (const float*)d_in[4];
    const int*   idx    = (const int*)d_in[5];
    const float* melw   = (const float*)d_in[6];
    const float* mask   = (const float*)d_in[7];
    const float* ola    = (const float*)d_in[8];
    float* out = (float*)d_out;

    const int W   = in_sizes[5] / K_BANDS;
    const int din = 2 * W;

    unsigned short* pre_wP  = (unsigned short*)d_ws;
    const size_t pre_bytes  = (size_t)K_BANDS * NKT1 * NCT1 * 64 * 8 * 2;
    unsigned short* post_wP = (unsigned short*)((char*)d_ws + pre_bytes);
    const size_t post_bytes = (size_t)K_BANDS * NKT2 * NCT2 * 64 * 8 * 2;
    float* post_bP = (float*)((char*)d_ws + pre_bytes + post_bytes);

    hipMemsetAsync(d_out, 0, (size_t)out_size * sizeof(float), stream);

    bs_pack_pre <<<dim3(K_BANDS, NKT1), 256, 0, stream>>>(pre_w, melw, mask,
                                                          pre_wP, W, din);
    bs_pack_post<<<dim3(K_BANDS, NKT2), 256, 0, stream>>>(post_w, post_b, idx,
                                                          melw, mask, ola,
                                                          post_wP, post_bP, W, din);

    dim3 grid(K_BANDS / 2, (B_DIM * T_DIM) / M_TILE);
    bs_main<0><<<grid, 256, 0, stream>>>(x, pre_wP, pre_b, post_wP, post_bP,
                                         idx, melw, mask, out, W);
    bs_main<1><<<grid, 256, 0, stream>>>(x, pre_wP, pre_b, post_wP, post_bP,
                                         idx, melw, mask, out, W);
}